// Round 1
// baseline (4663.834 us; speedup 1.0000x reference)
//
#include <hip/hip_runtime.h>
#include <hip/hip_bf16.h>

#define NTOK   8192
#define DMODEL 384
#define NHEAD  12
#define DHEAD  32
#define NLAYER 6
#define DFF    1536
#define SEQ    512
#define BATCH  16

__device__ __forceinline__ float sigmoidf_(float x){ return 1.f/(1.f+expf(-x)); }

// ---------------- embedding + LN ----------------
__global__ __launch_bounds__(128) void embed_ln_kernel(
    const int* __restrict__ ids, const float* __restrict__ tok,
    const float* __restrict__ pos, const float* __restrict__ typ,
    const float* __restrict__ g, const float* __restrict__ bvec, float* __restrict__ out)
{
  int n = blockIdx.x;
  int t = n & (SEQ-1);
  int id = ids[n];
  int tid = threadIdx.x;
  float v[3]; float s1=0.f, s2=0.f;
  #pragma unroll
  for (int j=0;j<3;j++){
    int d = tid + j*128;
    float x = tok[(long)id*DMODEL + d] + pos[t*DMODEL + d] + typ[d];
    v[j]=x; s1+=x; s2+=x*x;
  }
  #pragma unroll
  for (int m=1;m<64;m<<=1){ s1 += __shfl_xor(s1,m); s2 += __shfl_xor(s2,m); }
  __shared__ float r1[2], r2[2];
  if ((tid&63)==0){ r1[tid>>6]=s1; r2[tid>>6]=s2; }
  __syncthreads();
  s1 = r1[0]+r1[1]; s2 = r2[0]+r2[1];
  float mean = s1*(1.f/DMODEL);
  float var  = s2*(1.f/DMODEL) - mean*mean;
  float inv  = rsqrtf(var + 1e-12f);
  #pragma unroll
  for (int j=0;j<3;j++){
    int d = tid + j*128;
    out[(long)n*DMODEL + d] = (v[j]-mean)*inv*g[d] + bvec[d];
  }
}

// ---------------- residual add + LN (h = LN(h + res)) ----------------
__global__ __launch_bounds__(128) void add_ln_kernel(
    float* __restrict__ h, const float* __restrict__ res,
    const float* __restrict__ g, const float* __restrict__ bvec)
{
  int n = blockIdx.x;
  int tid = threadIdx.x;
  float v[3]; float s1=0.f, s2=0.f;
  #pragma unroll
  for (int j=0;j<3;j++){
    int d = tid + j*128;
    float x = h[(long)n*DMODEL + d] + res[(long)n*DMODEL + d];
    v[j]=x; s1+=x; s2+=x*x;
  }
  #pragma unroll
  for (int m=1;m<64;m<<=1){ s1 += __shfl_xor(s1,m); s2 += __shfl_xor(s2,m); }
  __shared__ float r1[2], r2[2];
  if ((tid&63)==0){ r1[tid>>6]=s1; r2[tid>>6]=s2; }
  __syncthreads();
  s1 = r1[0]+r1[1]; s2 = r2[0]+r2[1];
  float mean = s1*(1.f/DMODEL);
  float var  = s2*(1.f/DMODEL) - mean*mean;
  float inv  = rsqrtf(var + 1e-12f);
  #pragma unroll
  for (int j=0;j<3;j++){
    int d = tid + j*128;
    h[(long)n*DMODEL + d] = (v[j]-mean)*inv*g[d] + bvec[d];
  }
}

// ---------------- generic f32 GEMM: C[M,N] = act(X[M,K] @ W[K,N] + bias) ----------------
// BM=64, BN=64, BK=16, 256 threads, 4x4 per thread. M=8192, N%64==0, K%16==0.
// ACT: 0=none, 1=silu, 2=gelu(exact), 3=sigmoid
template<int ACT>
__global__ __launch_bounds__(256) void gemm_kernel(
    const float* __restrict__ X, const float* __restrict__ W,
    const float* __restrict__ bias, float* __restrict__ C, int Kd, int Nd)
{
  __shared__ float As[16][68];   // As[k][m]
  __shared__ float Bs[16][68];   // Bs[k][n]
  int tid = threadIdx.x;
  int bm = blockIdx.x*64, bn = blockIdx.y*64;
  int tx = tid & 15, ty = tid >> 4;
  float acc[4][4];
  #pragma unroll
  for (int i=0;i<4;i++){
    #pragma unroll
    for (int j=0;j<4;j++) acc[i][j]=0.f;
  }

  int xr = tid>>2, xk = (tid&3)<<2;      // X stage: row 0..63, k 0..15 (float4)
  int wk = tid>>4, wc = (tid&15)<<2;     // W stage: k 0..15, col 0..63 (float4)
  const float* xp = X + (long)(bm+xr)*Kd + xk;
  const float* wp = W + (long)wk*Nd + bn + wc;

  for (int k0=0; k0<Kd; k0+=16){
    float4 xa = *(const float4*)(xp + k0);
    float4 wa = *(const float4*)(wp + (long)k0*Nd);
    As[xk+0][xr]=xa.x; As[xk+1][xr]=xa.y; As[xk+2][xr]=xa.z; As[xk+3][xr]=xa.w;
    *(float4*)&Bs[wk][wc] = wa;
    __syncthreads();
    #pragma unroll
    for (int kk=0;kk<16;kk++){
      float4 a = *(const float4*)&As[kk][ty<<2];
      float4 b = *(const float4*)&Bs[kk][tx<<2];
      acc[0][0] += a.x*b.x; acc[0][1] += a.x*b.y; acc[0][2] += a.x*b.z; acc[0][3] += a.x*b.w;
      acc[1][0] += a.y*b.x; acc[1][1] += a.y*b.y; acc[1][2] += a.y*b.z; acc[1][3] += a.y*b.w;
      acc[2][0] += a.z*b.x; acc[2][1] += a.z*b.y; acc[2][2] += a.z*b.z; acc[2][3] += a.z*b.w;
      acc[3][0] += a.w*b.x; acc[3][1] += a.w*b.y; acc[3][2] += a.w*b.z; acc[3][3] += a.w*b.w;
    }
    __syncthreads();
  }

  #pragma unroll
  for (int i=0;i<4;i++){
    float4 o;
    #pragma unroll
    for (int j=0;j<4;j++){
      float c = acc[i][j] + (bias ? bias[bn+(tx<<2)+j] : 0.f);
      if (ACT==1)      c = c*sigmoidf_(c);
      else if (ACT==2) c = 0.5f*c*(1.f+erff(c*0.70710678118f));
      else if (ACT==3) c = sigmoidf_(c);
      ((float*)&o)[j] = c;
    }
    *(float4*)(C + (long)(bm+(ty<<2)+i)*Nd + bn + (tx<<2)) = o;
  }
}

// ---------------- per-(token,head) k normalization ----------------
__global__ __launch_bounds__(384) void knorm_kernel(float* __restrict__ K)
{
  int n = blockIdx.x; int tid = threadIdx.x;
  float x = K[(long)n*DMODEL + tid];
  float ss = x*x;
  #pragma unroll
  for (int m=1;m<32;m<<=1) ss += __shfl_xor(ss,m);
  K[(long)n*DMODEL + tid] = x / (sqrtf(ss)+1e-6f);
}

// ---------------- beta = sigmoid(x @ Wb + bb) * mask ----------------
__global__ __launch_bounds__(384) void beta_kernel(
    const float* __restrict__ X, const float* __restrict__ Wb, const float* __restrict__ bb,
    const int* __restrict__ mask, float* __restrict__ Bb)
{
  __shared__ float xs[DMODEL];
  int n = blockIdx.x; int tid = threadIdx.x;
  xs[tid] = X[(long)n*DMODEL + tid];
  __syncthreads();
  int hh = tid >> 5, i = tid & 31;
  float s = 0.f;
  for (int d=i; d<DMODEL; d+=32) s += xs[d]*Wb[d*NHEAD+hh];
  #pragma unroll
  for (int m=1;m<32;m<<=1) s += __shfl_xor(s,m);
  if (i==0) Bb[n*NHEAD+hh] = (float)mask[n] * sigmoidf_(s + bb[hh]);
}

// ---------------- delta-rule scan ----------------
// grid = 192 bh-pairs * 2 states = 384 blocks, 256 threads.
// thread: kg = tid&7 (owns k = 4*kg..4*kg+3), v = tid>>3 (0..31). State S[k][v] as float4.
__global__ __launch_bounds__(256) void scan_kernel(
    const float* __restrict__ Q, const float* __restrict__ K, const float* __restrict__ V,
    const float* __restrict__ Bb, const float* __restrict__ dlog_f, const float* __restrict__ dlog_s,
    float* __restrict__ Of, float* __restrict__ Os)
{
  int bid = blockIdx.x;
  int st = bid & 1;
  int bh = bid >> 1;
  int b = bh / NHEAD, hh = bh % NHEAD;
  float dec = sigmoidf_(st ? dlog_s[hh] : dlog_f[hh]);
  float* O = st ? Os : Of;
  int tid = threadIdx.x;
  int kg = tid & 7;
  int v  = tid >> 3;
  long base = (long)(b*SEQ)*DMODEL + hh*DHEAD;
  long bbase = (long)(b*SEQ)*NHEAD + hh;

  float4 S = make_float4(0.f,0.f,0.f,0.f);
  float4 kt = *(const float4*)(K + base + (kg<<2));
  float4 qt = *(const float4*)(Q + base + (kg<<2));
  float vt = V[base + v];
  float bt = Bb[bbase];

  for (int t=0; t<SEQ; ++t){
    float4 kn, qn; float vn=0.f, bn=0.f;
    if (t < SEQ-1){
      long a = base + (long)(t+1)*DMODEL;
      kn = *(const float4*)(K + a + (kg<<2));
      qn = *(const float4*)(Q + a + (kg<<2));
      vn = V[a + v];
      bn = Bb[bbase + (long)(t+1)*NHEAD];
    } else { kn = S; qn = S; }
    // p = sum_k kt[k]*S[k][v]
    float p = kt.x*S.x + kt.y*S.y + kt.z*S.z + kt.w*S.w;
    p += __shfl_xor(p,1); p += __shfl_xor(p,2); p += __shfl_xor(p,4);
    float err = (vt - p) * bt;
    S.x = dec*S.x + kt.x*err;
    S.y = dec*S.y + kt.y*err;
    S.z = dec*S.z + kt.z*err;
    S.w = dec*S.w + kt.w*err;
    float o = qt.x*S.x + qt.y*S.y + qt.z*S.z + qt.w*S.w;
    o += __shfl_xor(o,1); o += __shfl_xor(o,2); o += __shfl_xor(o,4);
    if (kg == 0) O[base + (long)t*DMODEL + v] = o;
    kt = kn; qt = qn; vt = vn; bt = bn;
  }
}

// ---------------- mix fast/slow + gate (G already sigmoided); writes into G ----------------
__global__ __launch_bounds__(256) void mixgate_kernel(
    const float* __restrict__ Of, const float* __restrict__ Os,
    const float* __restrict__ mixl, float* __restrict__ G)
{
  long idx = (long)blockIdx.x*blockDim.x + threadIdx.x;  // one float4
  long e = idx<<2;
  int d = (int)(e % DMODEL);
  int hh = d >> 5;
  float mix = sigmoidf_(mixl[hh]);
  float4 of = *(const float4*)(Of+e);
  float4 os = *(const float4*)(Os+e);
  float4 g  = *(const float4*)(G+e);
  float4 o;
  o.x = (mix*of.x + (1.f-mix)*os.x)*g.x;
  o.y = (mix*of.y + (1.f-mix)*os.y)*g.y;
  o.z = (mix*of.z + (1.f-mix)*os.z)*g.z;
  o.w = (mix*of.w + (1.f-mix)*os.w)*g.w;
  *(float4*)(G+e) = o;
}

// ---------------- masked mean pool + L2 normalize ----------------
__global__ __launch_bounds__(384) void pool_norm_kernel(
    const float* __restrict__ h, const int* __restrict__ mask, float* __restrict__ out)
{
  int b = blockIdx.x; int d = threadIdx.x;
  float s=0.f, ms=0.f;
  for (int t=0;t<SEQ;t++){
    float m = (float)mask[b*SEQ+t];
    s += h[((long)b*SEQ+t)*DMODEL + d]*m;
    ms += m;
  }
  float emb = s / fmaxf(ms, 1e-9f);
  float ss = emb*emb;
  #pragma unroll
  for (int m2=1;m2<64;m2<<=1) ss += __shfl_xor(ss,m2);
  __shared__ float r[6];
  if ((d&63)==0) r[d>>6]=ss;
  __syncthreads();
  ss = r[0]+r[1]+r[2]+r[3]+r[4]+r[5];
  out[b*DMODEL+d] = emb / (sqrtf(ss)+1e-12f);
}

extern "C" void kernel_launch(void* const* d_in, const int* in_sizes, int n_in,
                              void* d_out, int out_size, void* d_ws, size_t ws_size,
                              hipStream_t stream)
{
  const int*   ids   = (const int*)d_in[0];
  const int*   amask = (const int*)d_in[1];
  const float* etok  = (const float*)d_in[2];
  const float* epos  = (const float*)d_in[3];
  const float* etyp  = (const float*)d_in[4];
  const float* elng  = (const float*)d_in[5];
  const float* elnb  = (const float*)d_in[6];
  const float* Wq = (const float*)d_in[7];  const float* bq = (const float*)d_in[8];
  const float* Wk = (const float*)d_in[9];  const float* bk = (const float*)d_in[10];
  const float* Wv = (const float*)d_in[11]; const float* bv = (const float*)d_in[12];
  const float* Wb = (const float*)d_in[13]; const float* bb = (const float*)d_in[14];
  const float* dfl = (const float*)d_in[15];
  const float* dsl = (const float*)d_in[16];
  const float* mixl= (const float*)d_in[17];
  const float* Wg = (const float*)d_in[18];
  const float* Wo = (const float*)d_in[19]; const float* bo = (const float*)d_in[20];
  const float* alng = (const float*)d_in[21]; const float* alnb = (const float*)d_in[22];
  const float* W1 = (const float*)d_in[23]; const float* b1 = (const float*)d_in[24];
  const float* W2 = (const float*)d_in[25]; const float* b2 = (const float*)d_in[26];
  const float* flng = (const float*)d_in[27]; const float* flnb = (const float*)d_in[28];

  float* ws = (float*)d_ws;
  const long TD = (long)NTOK*DMODEL;
  float* h   = ws;
  float* Qb  = h   + TD;
  float* Kb  = Qb  + TD;
  float* Vb  = Kb  + TD;
  float* Gb  = Vb  + TD;
  float* Ofb = Gb  + TD;
  float* Osb = Ofb + TD;
  float* Bb  = Osb + TD;         // NTOK*NHEAD
  float* F1  = Qb;               // FFN intermediate aliases dead Q..G span (8192*1536)
  float* F2  = Ofb;              // FFN output aliases dead Of

  embed_ln_kernel<<<NTOK,128,0,stream>>>(ids, etok, epos, etyp, elng, elnb, h);

  for (int l=0;l<NLAYER;l++){
    const float* Wq_l = Wq + (long)l*DMODEL*DMODEL;
    const float* Wk_l = Wk + (long)l*DMODEL*DMODEL;
    const float* Wv_l = Wv + (long)l*DMODEL*DMODEL;
    const float* Wg_l = Wg + (long)l*DMODEL*DMODEL;
    const float* Wo_l = Wo + (long)l*DMODEL*DMODEL;

    gemm_kernel<1><<<dim3(128,6),256,0,stream>>>(h, Wq_l, bq+l*DMODEL, Qb, DMODEL, DMODEL);
    gemm_kernel<1><<<dim3(128,6),256,0,stream>>>(h, Wk_l, bk+l*DMODEL, Kb, DMODEL, DMODEL);
    knorm_kernel<<<NTOK,384,0,stream>>>(Kb);
    gemm_kernel<0><<<dim3(128,6),256,0,stream>>>(h, Wv_l, bv+l*DMODEL, Vb, DMODEL, DMODEL);
    gemm_kernel<3><<<dim3(128,6),256,0,stream>>>(h, Wg_l, nullptr, Gb, DMODEL, DMODEL);
    beta_kernel<<<NTOK,384,0,stream>>>(h, Wb + (long)l*DMODEL*NHEAD, bb + l*NHEAD, amask, Bb);
    scan_kernel<<<384,256,0,stream>>>(Qb, Kb, Vb, Bb, dfl + l*NHEAD, dsl + l*NHEAD, Ofb, Osb);
    mixgate_kernel<<<3072,256,0,stream>>>(Ofb, Osb, mixl + l*NHEAD, Gb);
    gemm_kernel<0><<<dim3(128,6),256,0,stream>>>(Gb, Wo_l, bo + l*DMODEL, Qb, DMODEL, DMODEL);
    add_ln_kernel<<<NTOK,128,0,stream>>>(h, Qb, alng + (long)l*DMODEL, alnb + (long)l*DMODEL);
    gemm_kernel<2><<<dim3(128,24),256,0,stream>>>(h, W1 + (long)l*DMODEL*DFF, b1 + (long)l*DFF, F1, DMODEL, DFF);
    gemm_kernel<0><<<dim3(128,6),256,0,stream>>>(F1, W2 + (long)l*DFF*DMODEL, b2 + (long)l*DMODEL, F2, DFF, DMODEL);
    add_ln_kernel<<<NTOK,128,0,stream>>>(h, F2, flng + (long)l*DMODEL, flnb + (long)l*DMODEL);
  }

  pool_norm_kernel<<<BATCH,384,0,stream>>>(h, amask, (float*)d_out);
}

// Round 2
// 2442.256 us; speedup vs baseline: 1.9096x; 1.9096x over previous
//
#include <hip/hip_runtime.h>
#include <hip/hip_bf16.h>

#define NTOK   8192
#define DMODEL 384
#define NHEAD  12
#define DHEAD  32
#define NLAYER 6
#define DFF    1536
#define SEQ    512
#define BATCH  16
#define TC     64

typedef __attribute__((ext_vector_type(8))) short short8;
typedef __attribute__((ext_vector_type(4))) float f32x4;

__device__ __forceinline__ float sigmoidf_(float x){ return 1.f/(1.f+expf(-x)); }

__device__ __forceinline__ ushort f2b(float x){
  uint b = __builtin_bit_cast(uint, x);
  uint r = (b + 0x7FFFu + ((b>>16)&1u)) >> 16;
  return (ushort)r;
}
__device__ __forceinline__ uint pk2(float lo, float hi){
  return (uint)f2b(lo) | ((uint)f2b(hi)<<16);
}

// ---------------- embedding + LN ----------------
__global__ __launch_bounds__(128) void embed_ln_kernel(
    const int* __restrict__ ids, const float* __restrict__ tok,
    const float* __restrict__ pos, const float* __restrict__ typ,
    const float* __restrict__ g, const float* __restrict__ bvec, float* __restrict__ out)
{
  int n = blockIdx.x;
  int t = n & (SEQ-1);
  int id = ids[n];
  int tid = threadIdx.x;
  float v[3]; float s1=0.f, s2=0.f;
  #pragma unroll
  for (int j=0;j<3;j++){
    int d = tid + j*128;
    float x = tok[(long)id*DMODEL + d] + pos[t*DMODEL + d] + typ[d];
    v[j]=x; s1+=x; s2+=x*x;
  }
  #pragma unroll
  for (int m=1;m<64;m<<=1){ s1 += __shfl_xor(s1,m); s2 += __shfl_xor(s2,m); }
  __shared__ float r1[2], r2[2];
  if ((tid&63)==0){ r1[tid>>6]=s1; r2[tid>>6]=s2; }
  __syncthreads();
  s1 = r1[0]+r1[1]; s2 = r2[0]+r2[1];
  float mean = s1*(1.f/DMODEL);
  float var  = s2*(1.f/DMODEL) - mean*mean;
  float inv  = rsqrtf(var + 1e-12f);
  #pragma unroll
  for (int j=0;j<3;j++){
    int d = tid + j*128;
    out[(long)n*DMODEL + d] = (v[j]-mean)*inv*g[d] + bvec[d];
  }
}

// ---------------- residual add + LN ----------------
__global__ __launch_bounds__(128) void add_ln_kernel(
    float* __restrict__ h, const float* __restrict__ res,
    const float* __restrict__ g, const float* __restrict__ bvec)
{
  int n = blockIdx.x;
  int tid = threadIdx.x;
  float v[3]; float s1=0.f, s2=0.f;
  #pragma unroll
  for (int j=0;j<3;j++){
    int d = tid + j*128;
    float x = h[(long)n*DMODEL + d] + res[(long)n*DMODEL + d];
    v[j]=x; s1+=x; s2+=x*x;
  }
  #pragma unroll
  for (int m=1;m<64;m<<=1){ s1 += __shfl_xor(s1,m); s2 += __shfl_xor(s2,m); }
  __shared__ float r1[2], r2[2];
  if ((tid&63)==0){ r1[tid>>6]=s1; r2[tid>>6]=s2; }
  __syncthreads();
  s1 = r1[0]+r1[1]; s2 = r2[0]+r2[1];
  float mean = s1*(1.f/DMODEL);
  float var  = s2*(1.f/DMODEL) - mean*mean;
  float inv  = rsqrtf(var + 1e-12f);
  #pragma unroll
  for (int j=0;j<3;j++){
    int d = tid + j*128;
    h[(long)n*DMODEL + d] = (v[j]-mean)*inv*g[d] + bvec[d];
  }
}

// ---------------- transpose + f32->bf16 convert: dst[N][K] <- src[K][N] ----------------
__global__ __launch_bounds__(256) void tcvt_kernel(const float* __restrict__ src,
    ushort* __restrict__ dst, int Kd, int Nd)
{
  __shared__ float tile[32][33];
  int t = threadIdx.x;
  int k0 = blockIdx.x<<5, n0 = blockIdx.y<<5;
  int r = t>>3, c4 = (t&7)<<2;
  const float* sp = src + (long)(k0+r)*Nd + n0 + c4;
  float4 f = *(const float4*)sp;
  tile[r][c4+0]=f.x; tile[r][c4+1]=f.y; tile[r][c4+2]=f.z; tile[r][c4+3]=f.w;
  __syncthreads();
  ushort4 o;
  o.x = f2b(tile[c4+0][r]); o.y = f2b(tile[c4+1][r]);
  o.z = f2b(tile[c4+2][r]); o.w = f2b(tile[c4+3][r]);
  *(ushort4*)(dst + (long)(n0+r)*Kd + k0 + c4) = o;
}

// ---------------- bf16 MFMA GEMM: C[M,N] = act(X[M,K]@W[K,N] + bias), WT = W^T bf16 [N][K]
// 256 thr (4 waves), tile 128x64, BK=32. Wave (wm,wn): 64x32 sub-tile, acc[4][2] 16x16 frags.
// ACT: 0 none, 1 silu, 2 gelu, 3 sigmoid. INBF: X is bf16. OUTBF: C stored bf16.
template<int ACT, int INBF, int OUTBF>
__global__ __launch_bounds__(256) void gemm_mfma(
    const void* __restrict__ Xv, const ushort* __restrict__ WT,
    const float* __restrict__ bias, void* __restrict__ Cv, int Kd, int Nd)
{
  __shared__ ushort A_lds[128][40];
  __shared__ ushort B_lds[64][40];
  int tid = threadIdx.x;
  int bm = blockIdx.x*128, bn = blockIdx.y*64;
  int w = tid>>6, lane = tid&63;
  int wm = w>>1, wn = w&1;
  f32x4 acc[4][2];
  #pragma unroll
  for (int i=0;i<4;i++){ acc[i][0]=(f32x4)(0.f); acc[i][1]=(f32x4)(0.f); }

  int arow = tid>>1, akk = (tid&1)*16;
  int brow = tid>>2, bkk = (tid&3)*8;
  const float*  Xf = (const float*)Xv;
  const ushort* Xb = (const ushort*)Xv;
  int cl = lane&15, koff = (lane>>4)*8;

  for (int k0=0; k0<Kd; k0+=32){
    if (INBF){
      const ushort* xp = Xb + (long)(bm+arow)*Kd + k0 + akk;
      uint4 v0 = *(const uint4*)xp;
      uint4 v1 = *(const uint4*)(xp+8);
      *(uint4*)&A_lds[arow][akk]   = v0;
      *(uint4*)&A_lds[arow][akk+8] = v1;
    } else {
      const float* xp = Xf + (long)(bm+arow)*Kd + k0 + akk;
      float4 f0 = *(const float4*)(xp+0);
      float4 f1 = *(const float4*)(xp+4);
      float4 f2 = *(const float4*)(xp+8);
      float4 f3 = *(const float4*)(xp+12);
      uint4 w0, w1;
      w0.x = pk2(f0.x,f0.y); w0.y = pk2(f0.z,f0.w);
      w0.z = pk2(f1.x,f1.y); w0.w = pk2(f1.z,f1.w);
      w1.x = pk2(f2.x,f2.y); w1.y = pk2(f2.z,f2.w);
      w1.z = pk2(f3.x,f3.y); w1.w = pk2(f3.z,f3.w);
      *(uint4*)&A_lds[arow][akk]   = w0;
      *(uint4*)&A_lds[arow][akk+8] = w1;
    }
    *(uint4*)&B_lds[brow][bkk] = *(const uint4*)(WT + (long)(bn+brow)*Kd + k0 + bkk);
    __syncthreads();
    short8 b0 = *(const short8*)&B_lds[wn*32 + cl][koff];
    short8 b1 = *(const short8*)&B_lds[wn*32 + 16 + cl][koff];
    #pragma unroll
    for (int mi=0; mi<4; mi++){
      short8 af = *(const short8*)&A_lds[wm*64 + mi*16 + cl][koff];
      acc[mi][0] = __builtin_amdgcn_mfma_f32_16x16x32_bf16(af, b0, acc[mi][0], 0,0,0);
      acc[mi][1] = __builtin_amdgcn_mfma_f32_16x16x32_bf16(af, b1, acc[mi][1], 0,0,0);
    }
    __syncthreads();
  }

  int rb = (lane>>4)*4;
  #pragma unroll
  for (int ni=0; ni<2; ni++){
    int col = bn + wn*32 + ni*16 + cl;
    float bsv = bias ? bias[col] : 0.f;
    #pragma unroll
    for (int mi=0; mi<4; mi++){
      #pragma unroll
      for (int j=0;j<4;j++){
        int row = bm + wm*64 + mi*16 + rb + j;
        float c = acc[mi][ni][j] + bsv;
        if (ACT==1)      c = c*sigmoidf_(c);
        else if (ACT==2) c = 0.5f*c*(1.f+erff(c*0.70710678118f));
        else if (ACT==3) c = sigmoidf_(c);
        if (OUTBF) ((ushort*)Cv)[(long)row*Nd + col] = f2b(c);
        else       ((float*)Cv)[(long)row*Nd + col] = c;
      }
    }
  }
}

// ---------------- per-(token,head) k normalization ----------------
__global__ __launch_bounds__(384) void knorm_kernel(float* __restrict__ K)
{
  int n = blockIdx.x; int tid = threadIdx.x;
  float x = K[(long)n*DMODEL + tid];
  float ss = x*x;
  #pragma unroll
  for (int m=1;m<32;m<<=1) ss += __shfl_xor(ss,m);
  K[(long)n*DMODEL + tid] = x / (sqrtf(ss)+1e-6f);
}

// ---------------- beta = sigmoid(x @ Wb + bb) * mask ----------------
__global__ __launch_bounds__(384) void beta_kernel(
    const float* __restrict__ X, const float* __restrict__ Wb, const float* __restrict__ bb,
    const int* __restrict__ mask, float* __restrict__ Bb)
{
  __shared__ float xs[DMODEL];
  int n = blockIdx.x; int tid = threadIdx.x;
  xs[tid] = X[(long)n*DMODEL + tid];
  __syncthreads();
  int hh = tid >> 5, i = tid & 31;
  float s = 0.f;
  for (int d=i; d<DMODEL; d+=32) s += xs[d]*Wb[d*NHEAD+hh];
  #pragma unroll
  for (int m=1;m<32;m<<=1) s += __shfl_xor(s,m);
  if (i==0) Bb[n*NHEAD+hh] = (float)mask[n] * sigmoidf_(s + bb[hh]);
}

// ---------------- delta-rule scan v2 ----------------
// 192 blocks = (b,h); 128 threads = 2 waves. wave0 = fast state, wave1 = slow state.
// lane: v = lane&31 (state column), kh = lane>>5 (k half, 16 k's per lane in regs).
__global__ __launch_bounds__(128) void scan2_kernel(
    const float* __restrict__ Q, const float* __restrict__ K, const float* __restrict__ V,
    const float* __restrict__ Bb, const float* __restrict__ dfl, const float* __restrict__ dsl,
    float* __restrict__ Of, float* __restrict__ Os)
{
  int bh = blockIdx.x;
  int b = bh / NHEAD, hh = bh - b*NHEAD;
  int tid = threadIdx.x;
  int wave = tid >> 6;
  int lane = tid & 63;
  int v = lane & 31;
  int kh = lane >> 5;
  float dec = sigmoidf_(wave ? dsl[hh] : dfl[hh]);
  float* O = wave ? Os : Of;
  long base  = (long)(b*SEQ)*DMODEL + hh*DHEAD;
  long bbase = (long)(b*SEQ)*NHEAD + hh;

  __shared__ float Kc[TC][32], Qc[TC][32], Vc[TC][32], Bc[TC];
  float S[16];
  #pragma unroll
  for (int i=0;i<16;i++) S[i]=0.f;

  for (int c=0; c<SEQ/TC; ++c){
    __syncthreads();
    #pragma unroll
    for (int j=0;j<4;j++){
      int flat = tid + 128*j;           // float4 index into [TC][8]
      int r = flat >> 3, cc = (flat & 7) << 2;
      long g = base + (long)(c*TC + r)*DMODEL + cc;
      *(float4*)&Kc[r][cc] = *(const float4*)(K + g);
      *(float4*)&Qc[r][cc] = *(const float4*)(Q + g);
      *(float4*)&Vc[r][cc] = *(const float4*)(V + g);
    }
    if (tid < TC) Bc[tid] = Bb[bbase + (long)(c*TC + tid)*NHEAD];
    __syncthreads();
    for (int t=0; t<TC; ++t){
      float kr[16], qr[16];
      #pragma unroll
      for (int j=0;j<4;j++){
        *(float4*)&kr[4*j] = *(const float4*)&Kc[t][kh*16 + 4*j];
        *(float4*)&qr[4*j] = *(const float4*)&Qc[t][kh*16 + 4*j];
      }
      float vt = Vc[t][v], bt = Bc[t];
      float p0=0.f,p1=0.f,p2=0.f,p3=0.f;
      #pragma unroll
      for (int j=0;j<4;j++){
        p0 += kr[4*j+0]*S[4*j+0]; p1 += kr[4*j+1]*S[4*j+1];
        p2 += kr[4*j+2]*S[4*j+2]; p3 += kr[4*j+3]*S[4*j+3];
      }
      float p = (p0+p1)+(p2+p3);
      p += __shfl_xor(p, 32);
      float err = (vt - p)*bt;
      #pragma unroll
      for (int j=0;j<16;j++) S[j] = dec*S[j] + kr[j]*err;
      float o0=0.f,o1=0.f,o2=0.f,o3=0.f;
      #pragma unroll
      for (int j=0;j<4;j++){
        o0 += qr[4*j+0]*S[4*j+0]; o1 += qr[4*j+1]*S[4*j+1];
        o2 += qr[4*j+2]*S[4*j+2]; o3 += qr[4*j+3]*S[4*j+3];
      }
      float o = (o0+o1)+(o2+o3);
      o += __shfl_xor(o, 32);
      if (kh==0) O[base + (long)(c*TC+t)*DMODEL + v] = o;
    }
  }
}

// ---------------- mix fast/slow + gate ----------------
__global__ __launch_bounds__(256) void mixgate_kernel(
    const float* __restrict__ Of, const float* __restrict__ Os,
    const float* __restrict__ mixl, float* __restrict__ G)
{
  long idx = (long)blockIdx.x*blockDim.x + threadIdx.x;
  long e = idx<<2;
  int d = (int)(e % DMODEL);
  int hh = d >> 5;
  float mix = sigmoidf_(mixl[hh]);
  float4 of = *(const float4*)(Of+e);
  float4 os = *(const float4*)(Os+e);
  float4 g  = *(const float4*)(G+e);
  float4 o;
  o.x = (mix*of.x + (1.f-mix)*os.x)*g.x;
  o.y = (mix*of.y + (1.f-mix)*os.y)*g.y;
  o.z = (mix*of.z + (1.f-mix)*os.z)*g.z;
  o.w = (mix*of.w + (1.f-mix)*os.w)*g.w;
  *(float4*)(G+e) = o;
}

// ---------------- masked mean pool + L2 normalize ----------------
__global__ __launch_bounds__(384) void pool_norm_kernel(
    const float* __restrict__ h, const int* __restrict__ mask, float* __restrict__ out)
{
  int b = blockIdx.x; int d = threadIdx.x;
  float s=0.f, ms=0.f;
  for (int t=0;t<SEQ;t++){
    float m = (float)mask[b*SEQ+t];
    s += h[((long)b*SEQ+t)*DMODEL + d]*m;
    ms += m;
  }
  float emb = s / fmaxf(ms, 1e-9f);
  float ss = emb*emb;
  #pragma unroll
  for (int m2=1;m2<64;m2<<=1) ss += __shfl_xor(ss,m2);
  __shared__ float r[6];
  if ((d&63)==0) r[d>>6]=ss;
  __syncthreads();
  ss = r[0]+r[1]+r[2]+r[3]+r[4]+r[5];
  out[b*DMODEL+d] = emb / (sqrtf(ss)+1e-12f);
}

extern "C" void kernel_launch(void* const* d_in, const int* in_sizes, int n_in,
                              void* d_out, int out_size, void* d_ws, size_t ws_size,
                              hipStream_t stream)
{
  const int*   ids   = (const int*)d_in[0];
  const int*   amask = (const int*)d_in[1];
  const float* etok  = (const float*)d_in[2];
  const float* epos  = (const float*)d_in[3];
  const float* etyp  = (const float*)d_in[4];
  const float* elng  = (const float*)d_in[5];
  const float* elnb  = (const float*)d_in[6];
  const float* Wq = (const float*)d_in[7];  const float* bq = (const float*)d_in[8];
  const float* Wk = (const float*)d_in[9];  const float* bk = (const float*)d_in[10];
  const float* Wv = (const float*)d_in[11]; const float* bv = (const float*)d_in[12];
  const float* Wb = (const float*)d_in[13]; const float* bb = (const float*)d_in[14];
  const float* dfl = (const float*)d_in[15];
  const float* dsl = (const float*)d_in[16];
  const float* mixl= (const float*)d_in[17];
  const float* Wg = (const float*)d_in[18];
  const float* Wo = (const float*)d_in[19]; const float* bo = (const float*)d_in[20];
  const float* alng = (const float*)d_in[21]; const float* alnb = (const float*)d_in[22];
  const float* W1 = (const float*)d_in[23]; const float* b1 = (const float*)d_in[24];
  const float* W2 = (const float*)d_in[25]; const float* b2 = (const float*)d_in[26];
  const float* flng = (const float*)d_in[27]; const float* flnb = (const float*)d_in[28];

  float* ws = (float*)d_ws;
  const long TD = (long)NTOK*DMODEL;
  float* h   = ws;
  float* Qb  = h   + TD;
  float* Kb  = Qb  + TD;
  float* Vb  = Kb  + TD;
  float* Gb  = Vb  + TD;
  float* Ofb = Gb  + TD;
  float* Rb  = Ofb + TD;            // Os during scan; Wo-out / FFN2-out afterwards
  float* Bb  = Rb  + TD;            // NTOK*NHEAD
  ushort* WT = (ushort*)(Bb + (long)NTOK*NHEAD);  // 589824 bf16 (1.18 MB), reused per GEMM
  ushort* F1B = (ushort*)Qb;        // FFN intermediate bf16, aliases dead Q+K exactly

  embed_ln_kernel<<<NTOK,128,0,stream>>>(ids, etok, epos, etyp, elng, elnb, h);

  for (int l=0;l<NLAYER;l++){
    const float* Wq_l = Wq + (long)l*DMODEL*DMODEL;
    const float* Wk_l = Wk + (long)l*DMODEL*DMODEL;
    const float* Wv_l = Wv + (long)l*DMODEL*DMODEL;
    const float* Wg_l = Wg + (long)l*DMODEL*DMODEL;
    const float* Wo_l = Wo + (long)l*DMODEL*DMODEL;
    const float* W1_l = W1 + (long)l*DMODEL*DFF;
    const float* W2_l = W2 + (long)l*DFF*DMODEL;

    tcvt_kernel<<<dim3(12,12),256,0,stream>>>(Wq_l, WT, DMODEL, DMODEL);
    gemm_mfma<1,0,0><<<dim3(64,6),256,0,stream>>>(h, WT, bq+l*DMODEL, Qb, DMODEL, DMODEL);
    tcvt_kernel<<<dim3(12,12),256,0,stream>>>(Wk_l, WT, DMODEL, DMODEL);
    gemm_mfma<1,0,0><<<dim3(64,6),256,0,stream>>>(h, WT, bk+l*DMODEL, Kb, DMODEL, DMODEL);
    knorm_kernel<<<NTOK,384,0,stream>>>(Kb);
    tcvt_kernel<<<dim3(12,12),256,0,stream>>>(Wv_l, WT, DMODEL, DMODEL);
    gemm_mfma<0,0,0><<<dim3(64,6),256,0,stream>>>(h, WT, bv+l*DMODEL, Vb, DMODEL, DMODEL);
    tcvt_kernel<<<dim3(12,12),256,0,stream>>>(Wg_l, WT, DMODEL, DMODEL);
    gemm_mfma<3,0,0><<<dim3(64,6),256,0,stream>>>(h, WT, nullptr, Gb, DMODEL, DMODEL);
    beta_kernel<<<NTOK,384,0,stream>>>(h, Wb + (long)l*DMODEL*NHEAD, bb + l*NHEAD, amask, Bb);
    scan2_kernel<<<BATCH*NHEAD,128,0,stream>>>(Qb, Kb, Vb, Bb, dfl + l*NHEAD, dsl + l*NHEAD, Ofb, Rb);
    mixgate_kernel<<<3072,256,0,stream>>>(Ofb, Rb, mixl + l*NHEAD, Gb);
    tcvt_kernel<<<dim3(12,12),256,0,stream>>>(Wo_l, WT, DMODEL, DMODEL);
    gemm_mfma<0,0,0><<<dim3(64,6),256,0,stream>>>(Gb, WT, bo + l*DMODEL, Rb, DMODEL, DMODEL);
    add_ln_kernel<<<NTOK,128,0,stream>>>(h, Rb, alng + (long)l*DMODEL, alnb + (long)l*DMODEL);
    tcvt_kernel<<<dim3(12,48),256,0,stream>>>(W1_l, WT, DMODEL, DFF);
    gemm_mfma<2,0,1><<<dim3(64,24),256,0,stream>>>(h, WT, b1 + (long)l*DFF, F1B, DMODEL, DFF);
    tcvt_kernel<<<dim3(48,12),256,0,stream>>>(W2_l, WT, DFF, DMODEL);
    gemm_mfma<0,1,0><<<dim3(64,6),256,0,stream>>>(F1B, WT, b2 + (long)l*DMODEL, Rb, DFF, DMODEL);
    add_ln_kernel<<<NTOK,128,0,stream>>>(h, Rb, flng + (long)l*DMODEL, flnb + (long)l*DMODEL);
  }

  pool_norm_kernel<<<BATCH,384,0,stream>>>(h, amask, (float*)d_out);
}

// Round 3
// 1967.438 us; speedup vs baseline: 2.3705x; 1.2413x over previous
//
#include <hip/hip_runtime.h>
#include <hip/hip_bf16.h>

#define NTOK   8192
#define DMODEL 384
#define NHEAD  12
#define DHEAD  32
#define NLAYER 6
#define DFF    1536
#define SEQ    512
#define BATCH  16
#define TC     64

typedef __attribute__((ext_vector_type(8))) short short8;
typedef __attribute__((ext_vector_type(4))) float f32x4;

__device__ __forceinline__ float sigmoidf_(float x){ return 1.f/(1.f+expf(-x)); }

__device__ __forceinline__ ushort f2b(float x){
  uint b = __builtin_bit_cast(uint, x);
  uint r = (b + 0x7FFFu + ((b>>16)&1u)) >> 16;
  return (ushort)r;
}
__device__ __forceinline__ uint pk2(float lo, float hi){
  return (uint)f2b(lo) | ((uint)f2b(hi)<<16);
}

// ---------------- embedding + LN ----------------
__global__ __launch_bounds__(128) void embed_ln_kernel(
    const int* __restrict__ ids, const float* __restrict__ tok,
    const float* __restrict__ pos, const float* __restrict__ typ,
    const float* __restrict__ g, const float* __restrict__ bvec, float* __restrict__ out)
{
  int n = blockIdx.x;
  int t = n & (SEQ-1);
  int id = ids[n];
  int tid = threadIdx.x;
  float v[3]; float s1=0.f, s2=0.f;
  #pragma unroll
  for (int j=0;j<3;j++){
    int d = tid + j*128;
    float x = tok[(long)id*DMODEL + d] + pos[t*DMODEL + d] + typ[d];
    v[j]=x; s1+=x; s2+=x*x;
  }
  #pragma unroll
  for (int m=1;m<64;m<<=1){ s1 += __shfl_xor(s1,m); s2 += __shfl_xor(s2,m); }
  __shared__ float r1[2], r2[2];
  if ((tid&63)==0){ r1[tid>>6]=s1; r2[tid>>6]=s2; }
  __syncthreads();
  s1 = r1[0]+r1[1]; s2 = r2[0]+r2[1];
  float mean = s1*(1.f/DMODEL);
  float var  = s2*(1.f/DMODEL) - mean*mean;
  float inv  = rsqrtf(var + 1e-12f);
  #pragma unroll
  for (int j=0;j<3;j++){
    int d = tid + j*128;
    out[(long)n*DMODEL + d] = (v[j]-mean)*inv*g[d] + bvec[d];
  }
}

// ---------------- residual add + LN ----------------
__global__ __launch_bounds__(128) void add_ln_kernel(
    float* __restrict__ h, const float* __restrict__ res,
    const float* __restrict__ g, const float* __restrict__ bvec)
{
  int n = blockIdx.x;
  int tid = threadIdx.x;
  float v[3]; float s1=0.f, s2=0.f;
  #pragma unroll
  for (int j=0;j<3;j++){
    int d = tid + j*128;
    float x = h[(long)n*DMODEL + d] + res[(long)n*DMODEL + d];
    v[j]=x; s1+=x; s2+=x*x;
  }
  #pragma unroll
  for (int m=1;m<64;m<<=1){ s1 += __shfl_xor(s1,m); s2 += __shfl_xor(s2,m); }
  __shared__ float r1[2], r2[2];
  if ((tid&63)==0){ r1[tid>>6]=s1; r2[tid>>6]=s2; }
  __syncthreads();
  s1 = r1[0]+r1[1]; s2 = r2[0]+r2[1];
  float mean = s1*(1.f/DMODEL);
  float var  = s2*(1.f/DMODEL) - mean*mean;
  float inv  = rsqrtf(var + 1e-12f);
  #pragma unroll
  for (int j=0;j<3;j++){
    int d = tid + j*128;
    h[(long)n*DMODEL + d] = (v[j]-mean)*inv*g[d] + bvec[d];
  }
}

// ---------------- per-layer weight transpose+convert into bf16 arena ----------------
// WTA layout (ushort offsets): QKVG rows[1536][384] @0; O rows[384][384] @589824;
// W1 rows[1536][384] @737280; W2 rows[384][1536] @1327104.
__global__ __launch_bounds__(256) void tcvt_all(
    const float* __restrict__ Wq_l, const float* __restrict__ Wk_l,
    const float* __restrict__ Wv_l, const float* __restrict__ Wg_l,
    const float* __restrict__ Wo_l, const float* __restrict__ W1_l,
    const float* __restrict__ W2_l, ushort* __restrict__ WTA)
{
  __shared__ float tile[32][33];
  int bid = blockIdx.x;
  const float* src; long dstbase; int rowlen, Nd, tk, tn, row0;
  if (bid < 720){
    int seg = bid/144, t = bid%144;
    tk = t%12; tn = t/12;
    src = (seg==0)?Wq_l:(seg==1)?Wk_l:(seg==2)?Wv_l:(seg==3)?Wg_l:Wo_l;
    Nd = 384; rowlen = 384;
    if (seg<4){ dstbase=0; row0=seg*384; }
    else      { dstbase=589824; row0=0; }
  } else if (bid < 1296){
    int t = bid-720; tk=t%12; tn=t/12;
    src=W1_l; Nd=DFF; dstbase=737280; row0=0; rowlen=384;
  } else {
    int t = bid-1296; tk=t%48; tn=t/48;
    src=W2_l; Nd=384; dstbase=1327104; row0=0; rowlen=DFF;
  }
  int k0=tk*32, n0=tn*32;
  int tt=threadIdx.x;
  int r=tt>>3, c4=(tt&7)<<2;
  const float* sp = src + (long)(k0+r)*Nd + n0 + c4;
  float4 f = *(const float4*)sp;
  tile[r][c4+0]=f.x; tile[r][c4+1]=f.y; tile[r][c4+2]=f.z; tile[r][c4+3]=f.w;
  __syncthreads();
  ushort4 o;
  o.x=f2b(tile[c4+0][r]); o.y=f2b(tile[c4+1][r]);
  o.z=f2b(tile[c4+2][r]); o.w=f2b(tile[c4+3][r]);
  *(ushort4*)(WTA + dstbase + (long)(row0+n0+r)*rowlen + k0 + c4) = o;
}

// ---------------- bf16 MFMA GEMM (as round 2, unchanged structure) ----------------
template<int ACT, int INBF, int OUTBF>
__global__ __launch_bounds__(256) void gemm_mfma(
    const void* __restrict__ Xv, const ushort* __restrict__ WT,
    const float* __restrict__ bias, void* __restrict__ Cv, int Kd, int Nd)
{
  __shared__ ushort A_lds[128][40];
  __shared__ ushort B_lds[64][40];
  int tid = threadIdx.x;
  int bm = blockIdx.x*128, bn = blockIdx.y*64;
  int w = tid>>6, lane = tid&63;
  int wm = w>>1, wn = w&1;
  f32x4 acc[4][2];
  #pragma unroll
  for (int i=0;i<4;i++){ acc[i][0]=(f32x4)(0.f); acc[i][1]=(f32x4)(0.f); }

  int arow = tid>>1, akk = (tid&1)*16;
  int brow = tid>>2, bkk = (tid&3)*8;
  const float*  Xf = (const float*)Xv;
  const ushort* Xb = (const ushort*)Xv;
  int cl = lane&15, koff = (lane>>4)*8;

  for (int k0=0; k0<Kd; k0+=32){
    if (INBF){
      const ushort* xp = Xb + (long)(bm+arow)*Kd + k0 + akk;
      *(uint4*)&A_lds[arow][akk]   = *(const uint4*)xp;
      *(uint4*)&A_lds[arow][akk+8] = *(const uint4*)(xp+8);
    } else {
      const float* xp = Xf + (long)(bm+arow)*Kd + k0 + akk;
      float4 f0 = *(const float4*)(xp+0);
      float4 f1 = *(const float4*)(xp+4);
      float4 f2 = *(const float4*)(xp+8);
      float4 f3 = *(const float4*)(xp+12);
      uint4 w0, w1;
      w0.x = pk2(f0.x,f0.y); w0.y = pk2(f0.z,f0.w);
      w0.z = pk2(f1.x,f1.y); w0.w = pk2(f1.z,f1.w);
      w1.x = pk2(f2.x,f2.y); w1.y = pk2(f2.z,f2.w);
      w1.z = pk2(f3.x,f3.y); w1.w = pk2(f3.z,f3.w);
      *(uint4*)&A_lds[arow][akk]   = w0;
      *(uint4*)&A_lds[arow][akk+8] = w1;
    }
    *(uint4*)&B_lds[brow][bkk] = *(const uint4*)(WT + (long)(bn+brow)*Kd + k0 + bkk);
    __syncthreads();
    short8 b0 = *(const short8*)&B_lds[wn*32 + cl][koff];
    short8 b1 = *(const short8*)&B_lds[wn*32 + 16 + cl][koff];
    #pragma unroll
    for (int mi=0; mi<4; mi++){
      short8 af = *(const short8*)&A_lds[wm*64 + mi*16 + cl][koff];
      acc[mi][0] = __builtin_amdgcn_mfma_f32_16x16x32_bf16(af, b0, acc[mi][0], 0,0,0);
      acc[mi][1] = __builtin_amdgcn_mfma_f32_16x16x32_bf16(af, b1, acc[mi][1], 0,0,0);
    }
    __syncthreads();
  }

  int rb = (lane>>4)*4;
  #pragma unroll
  for (int ni=0; ni<2; ni++){
    int col = bn + wn*32 + ni*16 + cl;
    float bsv = bias ? bias[col] : 0.f;
    #pragma unroll
    for (int mi=0; mi<4; mi++){
      #pragma unroll
      for (int j=0;j<4;j++){
        int row = bm + wm*64 + mi*16 + rb + j;
        float c = acc[mi][ni][j] + bsv;
        if (ACT==1)      c = c*sigmoidf_(c);
        else if (ACT==2) c = 0.5f*c*(1.f+erff(c*0.70710678118f));
        else if (ACT==3) c = sigmoidf_(c);
        if (OUTBF) ((ushort*)Cv)[(long)row*Nd + col] = f2b(c);
        else       ((float*)Cv)[(long)row*Nd + col] = c;
      }
    }
  }
}

// ---------------- fused QKVG GEMM: C[8192][1536] = acts(h @ [Wq|Wk|Wv|Wg] + b) ----------
// by 0-5: Q (silu,bq)  6-11: K (silu,bk)  12-17: V (none,bv)  18-23: G (sigmoid,none)
__global__ __launch_bounds__(256) void gemm_qkvg(
    const float* __restrict__ X, const ushort* __restrict__ WT,
    const float* __restrict__ bq, const float* __restrict__ bk,
    const float* __restrict__ bv, float* __restrict__ C)
{
  __shared__ ushort A_lds[128][40];
  __shared__ ushort B_lds[64][40];
  int tid = threadIdx.x;
  int bm = blockIdx.x*128, bn = blockIdx.y*64;
  int w = tid>>6, lane = tid&63;
  int wm = w>>1, wn = w&1;
  f32x4 acc[4][2];
  #pragma unroll
  for (int i=0;i<4;i++){ acc[i][0]=(f32x4)(0.f); acc[i][1]=(f32x4)(0.f); }
  int arow = tid>>1, akk = (tid&1)*16;
  int brow = tid>>2, bkk = (tid&3)*8;
  int cl = lane&15, koff = (lane>>4)*8;

  for (int k0=0; k0<DMODEL; k0+=32){
    const float* xp = X + (long)(bm+arow)*DMODEL + k0 + akk;
    float4 f0 = *(const float4*)(xp+0);
    float4 f1 = *(const float4*)(xp+4);
    float4 f2 = *(const float4*)(xp+8);
    float4 f3 = *(const float4*)(xp+12);
    uint4 w0, w1;
    w0.x = pk2(f0.x,f0.y); w0.y = pk2(f0.z,f0.w);
    w0.z = pk2(f1.x,f1.y); w0.w = pk2(f1.z,f1.w);
    w1.x = pk2(f2.x,f2.y); w1.y = pk2(f2.z,f2.w);
    w1.z = pk2(f3.x,f3.y); w1.w = pk2(f3.z,f3.w);
    *(uint4*)&A_lds[arow][akk]   = w0;
    *(uint4*)&A_lds[arow][akk+8] = w1;
    *(uint4*)&B_lds[brow][bkk] = *(const uint4*)(WT + (long)(bn+brow)*DMODEL + k0 + bkk);
    __syncthreads();
    short8 b0 = *(const short8*)&B_lds[wn*32 + cl][koff];
    short8 b1 = *(const short8*)&B_lds[wn*32 + 16 + cl][koff];
    #pragma unroll
    for (int mi=0; mi<4; mi++){
      short8 af = *(const short8*)&A_lds[wm*64 + mi*16 + cl][koff];
      acc[mi][0] = __builtin_amdgcn_mfma_f32_16x16x32_bf16(af, b0, acc[mi][0], 0,0,0);
      acc[mi][1] = __builtin_amdgcn_mfma_f32_16x16x32_bf16(af, b1, acc[mi][1], 0,0,0);
    }
    __syncthreads();
  }

  int by = blockIdx.y;
  int actid; const float* bp; int boff;
  if (by<6)      { actid=1; bp=bq; boff=0;    }
  else if (by<12){ actid=1; bp=bk; boff=384;  }
  else if (by<18){ actid=0; bp=bv; boff=768;  }
  else           { actid=3; bp=nullptr; boff=1152; }

  int rb = (lane>>4)*4;
  #pragma unroll
  for (int ni=0; ni<2; ni++){
    int col = bn + wn*32 + ni*16 + cl;
    float bsv = bp ? bp[col-boff] : 0.f;
    #pragma unroll
    for (int mi=0; mi<4; mi++){
      #pragma unroll
      for (int j=0;j<4;j++){
        int row = bm + wm*64 + mi*16 + rb + j;
        float c = acc[mi][ni][j] + bsv;
        if (actid==1)      c = c*sigmoidf_(c);
        else if (actid==3) c = sigmoidf_(c);
        C[(long)row*DFF + col] = c;
      }
    }
  }
}

// ---------------- beta = sigmoid(x @ Wb + bb) * mask ----------------
__global__ __launch_bounds__(384) void beta_kernel(
    const float* __restrict__ X, const float* __restrict__ Wb, const float* __restrict__ bb,
    const int* __restrict__ mask, float* __restrict__ Bb)
{
  __shared__ float xs[DMODEL];
  int n = blockIdx.x; int tid = threadIdx.x;
  xs[tid] = X[(long)n*DMODEL + tid];
  __syncthreads();
  int hh = tid >> 5, i = tid & 31;
  float s = 0.f;
  for (int d=i; d<DMODEL; d+=32) s += xs[d]*Wb[d*NHEAD+hh];
  #pragma unroll
  for (int m=1;m<32;m<<=1) s += __shfl_xor(s,m);
  if (i==0) Bb[n*NHEAD+hh] = (float)mask[n] * sigmoidf_(s + bb[hh]);
}

// ---------------- delta-rule scan v3 ----------------
// 192 blocks = (b,h); 256 thr = 4 waves: wave w: st = w>>1 (0 fast,1 slow), vhalf = w&1.
// lane: v = vhalf*16 + (lane>>2); kq = lane&3 owns k = kq*8..kq*8+7 (S[8] in regs).
// Fuses: k-normalization, mix, output gate, bf16 convert. Reads strided QKVG [*,1536].
__global__ __launch_bounds__(256) void scan3_kernel(
    const float* __restrict__ QKVG, const float* __restrict__ Bb,
    const float* __restrict__ dfl, const float* __restrict__ dsl,
    const float* __restrict__ mixl, ushort* __restrict__ OA)
{
  int bh = blockIdx.x;
  int b = bh / NHEAD, hh = bh - b*NHEAD;
  int tid = threadIdx.x;
  int w = tid>>6, lane = tid&63;
  int st = w>>1, vh = w&1;
  int v = vh*16 + (lane>>2);
  int kq = lane&3;
  float dec = sigmoidf_(st ? dsl[hh] : dfl[hh]);
  float mix = sigmoidf_(mixl[hh]);

  __shared__ float S4[4][TC][33];     // Q,K,V,G chunk (padded)
  __shared__ float Ofs[2][TC][34];
  __shared__ float Bc[TC];

  float S[8];
  #pragma unroll
  for (int i=0;i<8;i++) S[i]=0.f;

  long rowbase = (long)b*SEQ;
  for (int c=0;c<SEQ/TC;c++){
    __syncthreads();
    #pragma unroll
    for (int j=0;j<8;j++){
      int flat = tid + 256*j;          // 2048 float4 slots
      int arr = flat>>9, rem = flat&511;
      int r = rem>>3, c4 = (rem&7)<<2;
      long g = (rowbase + c*TC + r)*(long)DFF + arr*384 + hh*32 + c4;
      *(float4*)&S4[arr][r][c4] = *(const float4*)(QKVG + g);
    }
    if (tid < TC) Bc[tid] = Bb[(rowbase + c*TC + tid)*NHEAD + hh];
    __syncthreads();
    if (tid < TC){                     // k row normalization
      float ss=0.f;
      #pragma unroll
      for (int j=0;j<32;j++){ float x=S4[1][tid][j]; ss+=x*x; }
      float inv = 1.f/(sqrtf(ss)+1e-6f);
      #pragma unroll
      for (int j=0;j<32;j++) S4[1][tid][j]*=inv;
    }
    __syncthreads();
    #pragma unroll 4
    for (int t=0;t<TC;t++){
      float kr[8], qr[8];
      *(float4*)&kr[0] = *(const float4*)&S4[1][t][kq*8];
      *(float4*)&kr[4] = *(const float4*)&S4[1][t][kq*8+4];
      *(float4*)&qr[0] = *(const float4*)&S4[0][t][kq*8];
      *(float4*)&qr[4] = *(const float4*)&S4[0][t][kq*8+4];
      float vt = S4[2][t][v];
      float bt = Bc[t];
      float p0=0.f,p1=0.f;
      #pragma unroll
      for (int j=0;j<4;j++){ p0 += kr[2*j]*S[2*j]; p1 += kr[2*j+1]*S[2*j+1]; }
      float p = p0+p1;
      p += __shfl_xor(p,1); p += __shfl_xor(p,2);
      float err = (vt - p)*bt;
      #pragma unroll
      for (int j=0;j<8;j++) S[j] = dec*S[j] + kr[j]*err;
      float o0=0.f,o1=0.f;
      #pragma unroll
      for (int j=0;j<4;j++){ o0 += qr[2*j]*S[2*j]; o1 += qr[2*j+1]*S[2*j+1]; }
      float o = o0+o1;
      o += __shfl_xor(o,1); o += __shfl_xor(o,2);
      if (kq==0) Ofs[st][t][v] = o;
    }
    __syncthreads();
    {                                   // mix + gate + bf16 store
      int t = tid>>2, v0 = (tid&3)<<3;
      float of[8], os[8], gg[8];
      *(float4*)&of[0] = *(const float4*)&Ofs[0][t][v0];
      *(float4*)&of[4] = *(const float4*)&Ofs[0][t][v0+4];
      *(float4*)&os[0] = *(const float4*)&Ofs[1][t][v0];
      *(float4*)&os[4] = *(const float4*)&Ofs[1][t][v0+4];
      *(float4*)&gg[0] = *(const float4*)&S4[3][t][v0];
      *(float4*)&gg[4] = *(const float4*)&S4[3][t][v0+4];
      uint out4[4];
      #pragma unroll
      for (int j=0;j<4;j++){
        float a  = (mix*of[2*j]   + (1.f-mix)*os[2*j]  )*gg[2*j];
        float b2 = (mix*of[2*j+1] + (1.f-mix)*os[2*j+1])*gg[2*j+1];
        out4[j] = pk2(a,b2);
      }
      *(uint4*)(OA + (rowbase + c*TC + t)*DMODEL + hh*32 + v0) = *(uint4*)&out4[0];
    }
  }
}

// ---------------- masked mean pool + L2 normalize ----------------
__global__ __launch_bounds__(384) void pool_norm_kernel(
    const float* __restrict__ h, const int* __restrict__ mask, float* __restrict__ out)
{
  int b = blockIdx.x; int d = threadIdx.x;
  float s=0.f, ms=0.f;
  for (int t=0;t<SEQ;t++){
    float m = (float)mask[b*SEQ+t];
    s += h[((long)b*SEQ+t)*DMODEL + d]*m;
    ms += m;
  }
  float emb = s / fmaxf(ms, 1e-9f);
  float ss = emb*emb;
  #pragma unroll
  for (int m2=1;m2<64;m2<<=1) ss += __shfl_xor(ss,m2);
  __shared__ float r[6];
  if ((d&63)==0) r[d>>6]=ss;
  __syncthreads();
  ss = r[0]+r[1]+r[2]+r[3]+r[4]+r[5];
  out[b*DMODEL+d] = emb / (sqrtf(ss)+1e-12f);
}

extern "C" void kernel_launch(void* const* d_in, const int* in_sizes, int n_in,
                              void* d_out, int out_size, void* d_ws, size_t ws_size,
                              hipStream_t stream)
{
  const int*   ids   = (const int*)d_in[0];
  const int*   amask = (const int*)d_in[1];
  const float* etok  = (const float*)d_in[2];
  const float* epos  = (const float*)d_in[3];
  const float* etyp  = (const float*)d_in[4];
  const float* elng  = (const float*)d_in[5];
  const float* elnb  = (const float*)d_in[6];
  const float* Wq = (const float*)d_in[7];  const float* bq = (const float*)d_in[8];
  const float* Wk = (const float*)d_in[9];  const float* bk = (const float*)d_in[10];
  const float* Wv = (const float*)d_in[11]; const float* bv = (const float*)d_in[12];
  const float* Wb = (const float*)d_in[13]; const float* bb = (const float*)d_in[14];
  const float* dfl = (const float*)d_in[15];
  const float* dsl = (const float*)d_in[16];
  const float* mixl= (const float*)d_in[17];
  const float* Wg = (const float*)d_in[18];
  const float* Wo = (const float*)d_in[19]; const float* bo = (const float*)d_in[20];
  const float* alng = (const float*)d_in[21]; const float* alnb = (const float*)d_in[22];
  const float* W1 = (const float*)d_in[23]; const float* b1 = (const float*)d_in[24];
  const float* W2 = (const float*)d_in[25]; const float* b2 = (const float*)d_in[26];
  const float* flng = (const float*)d_in[27]; const float* flnb = (const float*)d_in[28];

  float* ws = (float*)d_ws;
  const long TD = (long)NTOK*DMODEL;
  float* h    = ws;
  float* QKVG = h + TD;                       // [8192][1536] f32
  ushort* OA  = (ushort*)(QKVG + 4*TD);       // [8192][384] bf16
  float* Rb   = QKVG + 4*TD + TD/2;           // Wo/FFN2 out f32
  float* Bb   = Rb + TD;                      // [8192][12]
  ushort* WTA = (ushort*)(Bb + (long)NTOK*NHEAD);  // 1,916,928 bf16
  ushort* F1B = (ushort*)QKVG;                // FFN mid bf16, aliases dead QKVG

  embed_ln_kernel<<<NTOK,128,0,stream>>>(ids, etok, epos, etyp, elng, elnb, h);

  for (int l=0;l<NLAYER;l++){
    tcvt_all<<<1872,256,0,stream>>>(
        Wq + (long)l*DMODEL*DMODEL, Wk + (long)l*DMODEL*DMODEL,
        Wv + (long)l*DMODEL*DMODEL, Wg + (long)l*DMODEL*DMODEL,
        Wo + (long)l*DMODEL*DMODEL, W1 + (long)l*DMODEL*DFF,
        W2 + (long)l*DFF*DMODEL, WTA);
    gemm_qkvg<<<dim3(64,24),256,0,stream>>>(h, WTA, bq+l*DMODEL, bk+l*DMODEL, bv+l*DMODEL, QKVG);
    beta_kernel<<<NTOK,384,0,stream>>>(h, Wb + (long)l*DMODEL*NHEAD, bb + l*NHEAD, amask, Bb);
    scan3_kernel<<<BATCH*NHEAD,256,0,stream>>>(QKVG, Bb, dfl + l*NHEAD, dsl + l*NHEAD, mixl + l*NHEAD, OA);
    gemm_mfma<0,1,0><<<dim3(64,6),256,0,stream>>>(OA, WTA+589824, bo + l*DMODEL, Rb, DMODEL, DMODEL);
    add_ln_kernel<<<NTOK,128,0,stream>>>(h, Rb, alng + (long)l*DMODEL, alnb + (long)l*DMODEL);
    gemm_mfma<2,0,1><<<dim3(64,24),256,0,stream>>>(h, WTA+737280, b1 + (long)l*DFF, F1B, DMODEL, DFF);
    gemm_mfma<0,1,0><<<dim3(64,6),256,0,stream>>>(F1B, WTA+1327104, b2 + (long)l*DMODEL, Rb, DFF, DMODEL);
    add_ln_kernel<<<NTOK,128,0,stream>>>(h, Rb, flng + (long)l*DMODEL, flnb + (long)l*DMODEL);
  }

  pool_norm_kernel<<<BATCH,384,0,stream>>>(h, amask, (float*)d_out);
}

// Round 4
// 1652.716 us; speedup vs baseline: 2.8219x; 1.1904x over previous
//
#include <hip/hip_runtime.h>
#include <hip/hip_bf16.h>

#define NTOK   8192
#define DMODEL 384
#define NHEAD  12
#define DHEAD  32
#define NLAYER 6
#define DFF    1536
#define SEQ    512
#define BATCH  16
#define TC     64

typedef __attribute__((ext_vector_type(8))) short short8;
typedef __attribute__((ext_vector_type(4))) float f32x4;

__device__ __forceinline__ float sigmoidf_(float x){ return 1.f/(1.f+expf(-x)); }

__device__ __forceinline__ ushort f2b(float x){
  uint b = __builtin_bit_cast(uint, x);
  uint r = (b + 0x7FFFu + ((b>>16)&1u)) >> 16;
  return (ushort)r;
}
__device__ __forceinline__ uint pk2(float lo, float hi){
  return (uint)f2b(lo) | ((uint)f2b(hi)<<16);
}

// intra-quad sum via DPP quad_perm (VALU-rate, no LDS pipe): lanes ^1 then ^2
__device__ __forceinline__ float quad_red(float x){
  int t = __builtin_amdgcn_update_dpp(0, __builtin_bit_cast(int,x), 0xB1, 0xF, 0xF, true);
  x += __builtin_bit_cast(float, t);
  t = __builtin_amdgcn_update_dpp(0, __builtin_bit_cast(int,x), 0x4E, 0xF, 0xF, true);
  x += __builtin_bit_cast(float, t);
  return x;
}

// ---------------- embedding + LN ----------------
__global__ __launch_bounds__(128) void embed_ln_kernel(
    const int* __restrict__ ids, const float* __restrict__ tok,
    const float* __restrict__ pos, const float* __restrict__ typ,
    const float* __restrict__ g, const float* __restrict__ bvec, float* __restrict__ out)
{
  int n = blockIdx.x;
  int t = n & (SEQ-1);
  int id = ids[n];
  int tid = threadIdx.x;
  float v[3]; float s1=0.f, s2=0.f;
  #pragma unroll
  for (int j=0;j<3;j++){
    int d = tid + j*128;
    float x = tok[(long)id*DMODEL + d] + pos[t*DMODEL + d] + typ[d];
    v[j]=x; s1+=x; s2+=x*x;
  }
  #pragma unroll
  for (int m=1;m<64;m<<=1){ s1 += __shfl_xor(s1,m); s2 += __shfl_xor(s2,m); }
  __shared__ float r1[2], r2[2];
  if ((tid&63)==0){ r1[tid>>6]=s1; r2[tid>>6]=s2; }
  __syncthreads();
  s1 = r1[0]+r1[1]; s2 = r2[0]+r2[1];
  float mean = s1*(1.f/DMODEL);
  float var  = s2*(1.f/DMODEL) - mean*mean;
  float inv  = rsqrtf(var + 1e-12f);
  #pragma unroll
  for (int j=0;j<3;j++){
    int d = tid + j*128;
    out[(long)n*DMODEL + d] = (v[j]-mean)*inv*g[d] + bvec[d];
  }
}

// ---------------- residual add + LN ----------------
__global__ __launch_bounds__(128) void add_ln_kernel(
    float* __restrict__ h, const float* __restrict__ res,
    const float* __restrict__ g, const float* __restrict__ bvec)
{
  int n = blockIdx.x;
  int tid = threadIdx.x;
  float v[3]; float s1=0.f, s2=0.f;
  #pragma unroll
  for (int j=0;j<3;j++){
    int d = tid + j*128;
    float x = h[(long)n*DMODEL + d] + res[(long)n*DMODEL + d];
    v[j]=x; s1+=x; s2+=x*x;
  }
  #pragma unroll
  for (int m=1;m<64;m<<=1){ s1 += __shfl_xor(s1,m); s2 += __shfl_xor(s2,m); }
  __shared__ float r1[2], r2[2];
  if ((tid&63)==0){ r1[tid>>6]=s1; r2[tid>>6]=s2; }
  __syncthreads();
  s1 = r1[0]+r1[1]; s2 = r2[0]+r2[1];
  float mean = s1*(1.f/DMODEL);
  float var  = s2*(1.f/DMODEL) - mean*mean;
  float inv  = rsqrtf(var + 1e-12f);
  #pragma unroll
  for (int j=0;j<3;j++){
    int d = tid + j*128;
    h[(long)n*DMODEL + d] = (v[j]-mean)*inv*g[d] + bvec[d];
  }
}

// ---------------- per-layer weight transpose+convert into bf16 arena ----------------
__global__ __launch_bounds__(256) void tcvt_all(
    const float* __restrict__ Wq_l, const float* __restrict__ Wk_l,
    const float* __restrict__ Wv_l, const float* __restrict__ Wg_l,
    const float* __restrict__ Wo_l, const float* __restrict__ W1_l,
    const float* __restrict__ W2_l, ushort* __restrict__ WTA)
{
  __shared__ float tile[32][33];
  int bid = blockIdx.x;
  const float* src; long dstbase; int rowlen, Nd, tk, tn, row0;
  if (bid < 720){
    int seg = bid/144, t = bid%144;
    tk = t%12; tn = t/12;
    src = (seg==0)?Wq_l:(seg==1)?Wk_l:(seg==2)?Wv_l:(seg==3)?Wg_l:Wo_l;
    Nd = 384; rowlen = 384;
    if (seg<4){ dstbase=0; row0=seg*384; }
    else      { dstbase=589824; row0=0; }
  } else if (bid < 1296){
    int t = bid-720; tk=t%12; tn=t/12;
    src=W1_l; Nd=DFF; dstbase=737280; row0=0; rowlen=384;
  } else {
    int t = bid-1296; tk=t%48; tn=t/48;
    src=W2_l; Nd=384; dstbase=1327104; row0=0; rowlen=DFF;
  }
  int k0=tk*32, n0=tn*32;
  int tt=threadIdx.x;
  int r=tt>>3, c4=(tt&7)<<2;
  const float* sp = src + (long)(k0+r)*Nd + n0 + c4;
  float4 f = *(const float4*)sp;
  tile[r][c4+0]=f.x; tile[r][c4+1]=f.y; tile[r][c4+2]=f.z; tile[r][c4+3]=f.w;
  __syncthreads();
  ushort4 o;
  o.x=f2b(tile[c4+0][r]); o.y=f2b(tile[c4+1][r]);
  o.z=f2b(tile[c4+2][r]); o.w=f2b(tile[c4+3][r]);
  *(ushort4*)(WTA + dstbase + (long)(row0+n0+r)*rowlen + k0 + c4) = o;
}

// ---------------- bf16 MFMA GEMM ----------------
template<int ACT, int INBF, int OUTBF>
__global__ __launch_bounds__(256) void gemm_mfma(
    const void* __restrict__ Xv, const ushort* __restrict__ WT,
    const float* __restrict__ bias, void* __restrict__ Cv, int Kd, int Nd)
{
  __shared__ ushort A_lds[128][40];
  __shared__ ushort B_lds[64][40];
  int tid = threadIdx.x;
  int bm = blockIdx.x*128, bn = blockIdx.y*64;
  int w = tid>>6, lane = tid&63;
  int wm = w>>1, wn = w&1;
  f32x4 acc[4][2];
  #pragma unroll
  for (int i=0;i<4;i++){ acc[i][0]=(f32x4)(0.f); acc[i][1]=(f32x4)(0.f); }

  int arow = tid>>1, akk = (tid&1)*16;
  int brow = tid>>2, bkk = (tid&3)*8;
  const float*  Xf = (const float*)Xv;
  const ushort* Xb = (const ushort*)Xv;
  int cl = lane&15, koff = (lane>>4)*8;

  for (int k0=0; k0<Kd; k0+=32){
    if (INBF){
      const ushort* xp = Xb + (long)(bm+arow)*Kd + k0 + akk;
      *(uint4*)&A_lds[arow][akk]   = *(const uint4*)xp;
      *(uint4*)&A_lds[arow][akk+8] = *(const uint4*)(xp+8);
    } else {
      const float* xp = Xf + (long)(bm+arow)*Kd + k0 + akk;
      float4 f0 = *(const float4*)(xp+0);
      float4 f1 = *(const float4*)(xp+4);
      float4 f2 = *(const float4*)(xp+8);
      float4 f3 = *(const float4*)(xp+12);
      uint4 w0, w1;
      w0.x = pk2(f0.x,f0.y); w0.y = pk2(f0.z,f0.w);
      w0.z = pk2(f1.x,f1.y); w0.w = pk2(f1.z,f1.w);
      w1.x = pk2(f2.x,f2.y); w1.y = pk2(f2.z,f2.w);
      w1.z = pk2(f3.x,f3.y); w1.w = pk2(f3.z,f3.w);
      *(uint4*)&A_lds[arow][akk]   = w0;
      *(uint4*)&A_lds[arow][akk+8] = w1;
    }
    *(uint4*)&B_lds[brow][bkk] = *(const uint4*)(WT + (long)(bn+brow)*Kd + k0 + bkk);
    __syncthreads();
    short8 b0 = *(const short8*)&B_lds[wn*32 + cl][koff];
    short8 b1 = *(const short8*)&B_lds[wn*32 + 16 + cl][koff];
    #pragma unroll
    for (int mi=0; mi<4; mi++){
      short8 af = *(const short8*)&A_lds[wm*64 + mi*16 + cl][koff];
      acc[mi][0] = __builtin_amdgcn_mfma_f32_16x16x32_bf16(af, b0, acc[mi][0], 0,0,0);
      acc[mi][1] = __builtin_amdgcn_mfma_f32_16x16x32_bf16(af, b1, acc[mi][1], 0,0,0);
    }
    __syncthreads();
  }

  int rb = (lane>>4)*4;
  #pragma unroll
  for (int ni=0; ni<2; ni++){
    int col = bn + wn*32 + ni*16 + cl;
    float bsv = bias ? bias[col] : 0.f;
    #pragma unroll
    for (int mi=0; mi<4; mi++){
      #pragma unroll
      for (int j=0;j<4;j++){
        int row = bm + wm*64 + mi*16 + rb + j;
        float c = acc[mi][ni][j] + bsv;
        if (ACT==1)      c = c*sigmoidf_(c);
        else if (ACT==2) c = 0.5f*c*(1.f+erff(c*0.70710678118f));
        else if (ACT==3) c = sigmoidf_(c);
        if (OUTBF) ((ushort*)Cv)[(long)row*Nd + col] = f2b(c);
        else       ((float*)Cv)[(long)row*Nd + col] = c;
      }
    }
  }
}

// ---------------- fused QKVG GEMM ----------------
__global__ __launch_bounds__(256) void gemm_qkvg(
    const float* __restrict__ X, const ushort* __restrict__ WT,
    const float* __restrict__ bq, const float* __restrict__ bk,
    const float* __restrict__ bv, float* __restrict__ C)
{
  __shared__ ushort A_lds[128][40];
  __shared__ ushort B_lds[64][40];
  int tid = threadIdx.x;
  int bm = blockIdx.x*128, bn = blockIdx.y*64;
  int w = tid>>6, lane = tid&63;
  int wm = w>>1, wn = w&1;
  f32x4 acc[4][2];
  #pragma unroll
  for (int i=0;i<4;i++){ acc[i][0]=(f32x4)(0.f); acc[i][1]=(f32x4)(0.f); }
  int arow = tid>>1, akk = (tid&1)*16;
  int brow = tid>>2, bkk = (tid&3)*8;
  int cl = lane&15, koff = (lane>>4)*8;

  for (int k0=0; k0<DMODEL; k0+=32){
    const float* xp = X + (long)(bm+arow)*DMODEL + k0 + akk;
    float4 f0 = *(const float4*)(xp+0);
    float4 f1 = *(const float4*)(xp+4);
    float4 f2 = *(const float4*)(xp+8);
    float4 f3 = *(const float4*)(xp+12);
    uint4 w0, w1;
    w0.x = pk2(f0.x,f0.y); w0.y = pk2(f0.z,f0.w);
    w0.z = pk2(f1.x,f1.y); w0.w = pk2(f1.z,f1.w);
    w1.x = pk2(f2.x,f2.y); w1.y = pk2(f2.z,f2.w);
    w1.z = pk2(f3.x,f3.y); w1.w = pk2(f3.z,f3.w);
    *(uint4*)&A_lds[arow][akk]   = w0;
    *(uint4*)&A_lds[arow][akk+8] = w1;
    *(uint4*)&B_lds[brow][bkk] = *(const uint4*)(WT + (long)(bn+brow)*DMODEL + k0 + bkk);
    __syncthreads();
    short8 b0 = *(const short8*)&B_lds[wn*32 + cl][koff];
    short8 b1 = *(const short8*)&B_lds[wn*32 + 16 + cl][koff];
    #pragma unroll
    for (int mi=0; mi<4; mi++){
      short8 af = *(const short8*)&A_lds[wm*64 + mi*16 + cl][koff];
      acc[mi][0] = __builtin_amdgcn_mfma_f32_16x16x32_bf16(af, b0, acc[mi][0], 0,0,0);
      acc[mi][1] = __builtin_amdgcn_mfma_f32_16x16x32_bf16(af, b1, acc[mi][1], 0,0,0);
    }
    __syncthreads();
  }

  int by = blockIdx.y;
  int actid; const float* bp; int boff;
  if (by<6)      { actid=1; bp=bq; boff=0;    }
  else if (by<12){ actid=1; bp=bk; boff=384;  }
  else if (by<18){ actid=0; bp=bv; boff=768;  }
  else           { actid=3; bp=nullptr; boff=1152; }

  int rb = (lane>>4)*4;
  #pragma unroll
  for (int ni=0; ni<2; ni++){
    int col = bn + wn*32 + ni*16 + cl;
    float bsv = bp ? bp[col-boff] : 0.f;
    #pragma unroll
    for (int mi=0; mi<4; mi++){
      #pragma unroll
      for (int j=0;j<4;j++){
        int row = bm + wm*64 + mi*16 + rb + j;
        float c = acc[mi][ni][j] + bsv;
        if (actid==1)      c = c*sigmoidf_(c);
        else if (actid==3) c = sigmoidf_(c);
        C[(long)row*DFF + col] = c;
      }
    }
  }
}

// ---------------- beta = sigmoid(x @ Wb + bb) * mask ----------------
__global__ __launch_bounds__(384) void beta_kernel(
    const float* __restrict__ X, const float* __restrict__ Wb, const float* __restrict__ bb,
    const int* __restrict__ mask, float* __restrict__ Bb)
{
  __shared__ float xs[DMODEL];
  int n = blockIdx.x; int tid = threadIdx.x;
  xs[tid] = X[(long)n*DMODEL + tid];
  __syncthreads();
  int hh = tid >> 5, i = tid & 31;
  float s = 0.f;
  for (int d=i; d<DMODEL; d+=32) s += xs[d]*Wb[d*NHEAD+hh];
  #pragma unroll
  for (int m=1;m<32;m<<=1) s += __shfl_xor(s,m);
  if (i==0) Bb[n*NHEAD+hh] = (float)mask[n] * sigmoidf_(s + bb[hh]);
}

// ---------------- delta-rule scan v4: DPP quad reductions + explicit prefetch ----------
// 192 blocks = (b,h); 256 thr = 4 waves: wave w: st = w>>1 (0 fast,1 slow), vhalf = w&1.
// lane: v = vhalf*16 + (lane>>2); kq = lane&3 owns k = kq*8..kq*8+7 (S[8] in regs).
__global__ __launch_bounds__(256) void scan4_kernel(
    const float* __restrict__ QKVG, const float* __restrict__ Bb,
    const float* __restrict__ dfl, const float* __restrict__ dsl,
    const float* __restrict__ mixl, ushort* __restrict__ OA)
{
  int bh = blockIdx.x;
  int b = bh / NHEAD, hh = bh - b*NHEAD;
  int tid = threadIdx.x;
  int w = tid>>6, lane = tid&63;
  int st = w>>1, vh = w&1;
  int v = vh*16 + (lane>>2);
  int kq = lane&3;
  float dec = sigmoidf_(st ? dsl[hh] : dfl[hh]);
  float mix = sigmoidf_(mixl[hh]);

  __shared__ float S4[4][TC][33];     // Q,K,V,G chunk (padded)
  __shared__ float Ofs[2][TC][34];
  __shared__ float Bc[TC];

  float S[8];
  #pragma unroll
  for (int i=0;i<8;i++) S[i]=0.f;

  long rowbase = (long)b*SEQ;
  for (int c=0;c<SEQ/TC;c++){
    __syncthreads();
    #pragma unroll
    for (int j=0;j<8;j++){
      int flat = tid + 256*j;
      int arr = flat>>9, rem = flat&511;
      int r = rem>>3, c4 = (rem&7)<<2;
      long g = (rowbase + c*TC + r)*(long)DFF + arr*384 + hh*32 + c4;
      *(float4*)&S4[arr][r][c4] = *(const float4*)(QKVG + g);
    }
    if (tid < TC) Bc[tid] = Bb[(rowbase + c*TC + tid)*NHEAD + hh];
    __syncthreads();
    if (tid < TC){                     // k row normalization
      float ss=0.f;
      #pragma unroll
      for (int j=0;j<32;j++){ float x=S4[1][tid][j]; ss+=x*x; }
      float inv = 1.f/(sqrtf(ss)+1e-6f);
      #pragma unroll
      for (int j=0;j<32;j++) S4[1][tid][j]*=inv;
    }
    __syncthreads();

    float kr[8], qr[8];
    *(float4*)&kr[0] = *(const float4*)&S4[1][0][kq*8];
    *(float4*)&kr[4] = *(const float4*)&S4[1][0][kq*8+4];
    *(float4*)&qr[0] = *(const float4*)&S4[0][0][kq*8];
    *(float4*)&qr[4] = *(const float4*)&S4[0][0][kq*8+4];
    float vt = S4[2][0][v];
    float bt = Bc[0];

    #pragma unroll 4
    for (int t=0;t<TC;t++){
      // prefetch t+1 (same-row reload at t=TC-1; off the critical chain)
      int tn = (t+1<TC)?(t+1):t;
      float krn[8], qrn[8];
      *(float4*)&krn[0] = *(const float4*)&S4[1][tn][kq*8];
      *(float4*)&krn[4] = *(const float4*)&S4[1][tn][kq*8+4];
      *(float4*)&qrn[0] = *(const float4*)&S4[0][tn][kq*8];
      *(float4*)&qrn[4] = *(const float4*)&S4[0][tn][kq*8+4];
      float vn = S4[2][tn][v];
      float bn = Bc[tn];

      float p0=0.f,p1=0.f;
      #pragma unroll
      for (int j=0;j<4;j++){ p0 += kr[2*j]*S[2*j]; p1 += kr[2*j+1]*S[2*j+1]; }
      float p = quad_red(p0+p1);
      float err = (vt - p)*bt;
      #pragma unroll
      for (int j=0;j<8;j++) S[j] = dec*S[j] + kr[j]*err;
      float o0=0.f,o1=0.f;
      #pragma unroll
      for (int j=0;j<4;j++){ o0 += qr[2*j]*S[2*j]; o1 += qr[2*j+1]*S[2*j+1]; }
      float o = quad_red(o0+o1);
      if (kq==0) Ofs[st][t][v] = o;

      #pragma unroll
      for (int j=0;j<8;j++){ kr[j]=krn[j]; qr[j]=qrn[j]; }
      vt = vn; bt = bn;
    }
    __syncthreads();
    {                                   // mix + gate + bf16 store
      int t = tid>>2, v0 = (tid&3)<<3;
      float of[8], os[8], gg[8];
      *(float4*)&of[0] = *(const float4*)&Ofs[0][t][v0];
      *(float4*)&of[4] = *(const float4*)&Ofs[0][t][v0+4];
      *(float4*)&os[0] = *(const float4*)&Ofs[1][t][v0];
      *(float4*)&os[4] = *(const float4*)&Ofs[1][t][v0+4];
      *(float4*)&gg[0] = *(const float4*)&S4[3][t][v0];
      *(float4*)&gg[4] = *(const float4*)&S4[3][t][v0+4];
      uint out4[4];
      #pragma unroll
      for (int j=0;j<4;j++){
        float a  = (mix*of[2*j]   + (1.f-mix)*os[2*j]  )*gg[2*j];
        float b2 = (mix*of[2*j+1] + (1.f-mix)*os[2*j+1])*gg[2*j+1];
        out4[j] = pk2(a,b2);
      }
      *(uint4*)(OA + (rowbase + c*TC + t)*DMODEL + hh*32 + v0) = *(uint4*)&out4[0];
    }
  }
}

// ---------------- masked mean pool + L2 normalize ----------------
__global__ __launch_bounds__(384) void pool_norm_kernel(
    const float* __restrict__ h, const int* __restrict__ mask, float* __restrict__ out)
{
  int b = blockIdx.x; int d = threadIdx.x;
  float s=0.f, ms=0.f;
  for (int t=0;t<SEQ;t++){
    float m = (float)mask[b*SEQ+t];
    s += h[((long)b*SEQ+t)*DMODEL + d]*m;
    ms += m;
  }
  float emb = s / fmaxf(ms, 1e-9f);
  float ss = emb*emb;
  #pragma unroll
  for (int m2=1;m2<64;m2<<=1) ss += __shfl_xor(ss,m2);
  __shared__ float r[6];
  if ((d&63)==0) r[d>>6]=ss;
  __syncthreads();
  ss = r[0]+r[1]+r[2]+r[3]+r[4]+r[5];
  out[b*DMODEL+d] = emb / (sqrtf(ss)+1e-12f);
}

extern "C" void kernel_launch(void* const* d_in, const int* in_sizes, int n_in,
                              void* d_out, int out_size, void* d_ws, size_t ws_size,
                              hipStream_t stream)
{
  const int*   ids   = (const int*)d_in[0];
  const int*   amask = (const int*)d_in[1];
  const float* etok  = (const float*)d_in[2];
  const float* epos  = (const float*)d_in[3];
  const float* etyp  = (const float*)d_in[4];
  const float* elng  = (const float*)d_in[5];
  const float* elnb  = (const float*)d_in[6];
  const float* Wq = (const float*)d_in[7];  const float* bq = (const float*)d_in[8];
  const float* Wk = (const float*)d_in[9];  const float* bk = (const float*)d_in[10];
  const float* Wv = (const float*)d_in[11]; const float* bv = (const float*)d_in[12];
  const float* Wb = (const float*)d_in[13]; const float* bb = (const float*)d_in[14];
  const float* dfl = (const float*)d_in[15];
  const float* dsl = (const float*)d_in[16];
  const float* mixl= (const float*)d_in[17];
  const float* Wg = (const float*)d_in[18];
  const float* Wo = (const float*)d_in[19]; const float* bo = (const float*)d_in[20];
  const float* alng = (const float*)d_in[21]; const float* alnb = (const float*)d_in[22];
  const float* W1 = (const float*)d_in[23]; const float* b1 = (const float*)d_in[24];
  const float* W2 = (const float*)d_in[25]; const float* b2 = (const float*)d_in[26];
  const float* flng = (const float*)d_in[27]; const float* flnb = (const float*)d_in[28];

  float* ws = (float*)d_ws;
  const long TD = (long)NTOK*DMODEL;
  float* h    = ws;
  float* QKVG = h + TD;                       // [8192][1536] f32
  ushort* OA  = (ushort*)(QKVG + 4*TD);       // [8192][384] bf16
  float* Rb   = QKVG + 4*TD + TD/2;           // Wo/FFN2 out f32
  float* Bb   = Rb + TD;                      // [8192][12]
  ushort* WTA = (ushort*)(Bb + (long)NTOK*NHEAD);
  ushort* F1B = (ushort*)QKVG;                // FFN mid bf16, aliases dead QKVG

  embed_ln_kernel<<<NTOK,128,0,stream>>>(ids, etok, epos, etyp, elng, elnb, h);

  for (int l=0;l<NLAYER;l++){
    tcvt_all<<<1872,256,0,stream>>>(
        Wq + (long)l*DMODEL*DMODEL, Wk + (long)l*DMODEL*DMODEL,
        Wv + (long)l*DMODEL*DMODEL, Wg + (long)l*DMODEL*DMODEL,
        Wo + (long)l*DMODEL*DMODEL, W1 + (long)l*DMODEL*DFF,
        W2 + (long)l*DFF*DMODEL, WTA);
    gemm_qkvg<<<dim3(64,24),256,0,stream>>>(h, WTA, bq+l*DMODEL, bk+l*DMODEL, bv+l*DMODEL, QKVG);
    beta_kernel<<<NTOK,384,0,stream>>>(h, Wb + (long)l*DMODEL*NHEAD, bb + l*NHEAD, amask, Bb);
    scan4_kernel<<<BATCH*NHEAD,256,0,stream>>>(QKVG, Bb, dfl + l*NHEAD, dsl + l*NHEAD, mixl + l*NHEAD, OA);
    gemm_mfma<0,1,0><<<dim3(64,6),256,0,stream>>>(OA, WTA+589824, bo + l*DMODEL, Rb, DMODEL, DMODEL);
    add_ln_kernel<<<NTOK,128,0,stream>>>(h, Rb, alng + (long)l*DMODEL, alnb + (long)l*DMODEL);
    gemm_mfma<2,0,1><<<dim3(64,24),256,0,stream>>>(h, WTA+737280, b1 + (long)l*DFF, F1B, DMODEL, DFF);
    gemm_mfma<0,1,0><<<dim3(64,6),256,0,stream>>>(F1B, WTA+1327104, b2 + (long)l*DMODEL, Rb, DFF, DMODEL);
    add_ln_kernel<<<NTOK,128,0,stream>>>(h, Rb, flng + (long)l*DMODEL, flnb + (long)l*DMODEL);
  }

  pool_norm_kernel<<<BATCH,384,0,stream>>>(h, amask, (float*)d_out);
}